// Round 7
// baseline (516.224 us; speedup 1.0000x reference)
//
#include <hip/hip_runtime.h>
#include <stdint.h>

typedef _Float16 f16;
typedef __attribute__((ext_vector_type(8))) _Float16 f16x8;
typedef __attribute__((ext_vector_type(4))) _Float16 f16x4;
typedef __attribute__((ext_vector_type(4))) float f32x4;

// Tiled weight layout in ws (f16 elems), K-tile = 32, tiles n-major [n][32]:
// W1: 4  tiles of [512][32] @ WS_W1; W2: 16 tiles of [512][32] @ WS_W2;
// W3: 16 tiles of [256][32] @ WS_W3 (n>=251 zeroed).
// Wave w's slice of each tile (its 16*NT output cols) is contiguous (NT*1024B).
#define WS_W1 0
#define WS_W2 65536
#define WS_W3 327680

__global__ __launch_bounds__(256) void convert_weights_k(
    const float* __restrict__ W1, const float* __restrict__ W2,
    const float* __restrict__ W3, f16* __restrict__ ws)
{
  int idx = blockIdx.x * 256 + threadIdx.x;
  if (idx < 65536) {
    int kt = idx >> 14, r = idx & 16383, n = r >> 5, kk = r & 31;
    ws[WS_W1 + idx] = (f16)W1[(kt * 32 + kk) * 512 + n];
  } else if (idx < 327680) {
    int i = idx - 65536;
    int kt = i >> 14, r = i & 16383, n = r >> 5, kk = r & 31;
    ws[WS_W2 + i] = (f16)W2[(kt * 32 + kk) * 512 + n];
  } else if (idx < 458752) {
    int i = idx - 327680;
    int kt = i >> 13, r = i & 8191, n = r >> 5, kk = r & 31;
    ws[WS_W3 + i] = (n < 251) ? (f16)W3[(kt * 32 + kk) * 251 + n] : (f16)0.0f;
  }
}

// Swizzled LDS vector read: 16B at row m, byte offset kb (16B aligned)
__device__ __forceinline__ f16x8 lds_ld8(const char* base, int m, int strideB, int kb) {
  return *(const f16x8*)(base + m * strideB + (kb ^ ((m & 7) << 4)));
}

// x-fragment (8 consecutive elems of concat(obs[96],act[32])) direct from HBM.
// e is a multiple of 8; the 96-boundary is never spanned.
__device__ __forceinline__ f16x8 load_x_frag(
    const float* __restrict__ obs, const float* __restrict__ act, long row, int e)
{
  const float* p = (e < 96) ? (obs + row * 96 + e) : (act + row * 32 + (e - 96));
  float4 lo = ((const float4*)p)[0];
  float4 hi = ((const float4*)p)[1];
  f16x8 v;
  v[0] = (f16)lo.x; v[1] = (f16)lo.y; v[2] = (f16)lo.z; v[3] = (f16)lo.w;
  v[4] = (f16)hi.x; v[5] = (f16)hi.y; v[6] = (f16)hi.z; v[7] = (f16)hi.w;
  return v;
}

// --------------------------- GEMM building blocks ---------------------------
// Weights stream global->VGPR (L2-resident, per-wave contiguous slice):
// DS pipe is reserved for the activation (B) reads only.
template<int KT, int NT>
__device__ __forceinline__ void mlp_stage_reg(
    const char* __restrict__ wlane, int tileB,
    const char* __restrict__ src, int srcStride,
    f32x4 acc[4][NT], int l15, int lh)
{
  #pragma unroll
  for (int kt = 0; kt < KT; ++kt) {
    f16x8 a[NT];
    const char* g = wlane + (size_t)kt * tileB;
    #pragma unroll
    for (int nt = 0; nt < NT; ++nt) a[nt] = *(const f16x8*)(g + nt * 1024);
    __builtin_amdgcn_s_setprio(1);
    #pragma unroll
    for (int mh = 0; mh < 4; ++mh) {
      f16x8 b = lds_ld8(src, mh * 16 + l15, srcStride, kt * 64 + lh * 16);
      #pragma unroll
      for (int nt = 0; nt < NT; ++nt)
        acc[mh][nt] = __builtin_amdgcn_mfma_f32_16x16x32_f16(a[nt], b, acc[mh][nt], 0, 0, 0);
    }
    __builtin_amdgcn_s_setprio(0);
  }
}

// Stage 1: B-operand loaded straight from obs/act (no LDS at all).
__device__ __forceinline__ void mlp_stage1(
    const float* __restrict__ obs, const float* __restrict__ act, long rowBase,
    const char* __restrict__ wlane, f32x4 acc[4][4], int l15, int lh)
{
  #pragma unroll
  for (int kt = 0; kt < 4; ++kt) {
    f16x8 a[4];
    const char* g = wlane + (size_t)kt * 32768;
    #pragma unroll
    for (int nt = 0; nt < 4; ++nt) a[nt] = *(const f16x8*)(g + nt * 1024);
    int e = kt * 32 + lh * 8;
    #pragma unroll
    for (int mh = 0; mh < 4; ++mh) {
      f16x8 b = load_x_frag(obs, act, rowBase + mh * 16 + l15, e);
      #pragma unroll
      for (int nt = 0; nt < 4; ++nt)
        acc[mh][nt] = __builtin_amdgcn_mfma_f32_16x16x32_f16(a[nt], b, acc[mh][nt], 0, 0, 0);
    }
  }
}

template<int NT>
__device__ __forceinline__ void store_act(
    f32x4 acc[4][NT], char* hbuf, const float* __restrict__ bias,
    int w, int l15, int lh)
{
  #pragma unroll
  for (int nt = 0; nt < NT; ++nt) {
    int ncol = w * (NT * 16) + nt * 16 + lh * 4;
    f32x4 bv = *(const f32x4*)(bias + ncol);
    #pragma unroll
    for (int mh = 0; mh < 4; ++mh) {
      int m = mh * 16 + l15;
      f16x4 hv;
      #pragma unroll
      for (int r = 0; r < 4; ++r) {
        float v = acc[mh][nt][r] + bv[r];
        hv[r] = (f16)(v > 0.f ? v : 0.01f * v);
      }
      *(f16x4*)(hbuf + m * 1024 + ((ncol * 2) ^ ((m & 7) << 4))) = hv;
    }
  }
}

// Stage-3 store: TRANSPOSED logits lgT[atom][row] (f32), b3 folded in,
// atoms >= 251 padded with -3e38.
__device__ __forceinline__ void store_logits_T(
    f32x4 acc[4][2], float* lgT, const float* __restrict__ bias3,
    int w, int l15, int lh)
{
  #pragma unroll
  for (int nt = 0; nt < 2; ++nt) {
    int abase = w * 32 + nt * 16 + lh * 4;
    float bv[4];
    #pragma unroll
    for (int r = 0; r < 4; ++r) {
      int a = abase + r;
      bv[r] = (a < 251) ? bias3[a] : 0.f;
    }
    #pragma unroll
    for (int mh = 0; mh < 4; ++mh) {
      int m = mh * 16 + l15;
      #pragma unroll
      for (int r = 0; r < 4; ++r) {
        int a = abase + r;
        lgT[a * 64 + m] = (a < 251) ? (acc[mh][nt][r] + bv[r]) : -3.0e38f;
      }
    }
  }
}

// ------------------------------- fused kernel -------------------------------
// LDS: hbuf 64KB (h1 -> h2 -> lgT -> prT overlay) + pmax/psum 4KB = 68KB
// -> 2 blocks/CU truly resident (launch_bounds(512,4) caps regs at 128).
__global__ __launch_bounds__(512, 4) void fused_c51_k(
    const float* __restrict__ obs, const float* __restrict__ act,
    const float* __restrict__ rewards, const float* __restrict__ bootstrap,
    const float* __restrict__ discount, const float* __restrict__ q_support,
    const float* __restrict__ bias1, const float* __restrict__ bias2,
    const float* __restrict__ bias3, const f16* __restrict__ ws,
    float* __restrict__ out)
{
  extern __shared__ char smem[];
  char* hbuf = smem;                       // 64KB
  float* pmax = (float*)(smem + 65536);    // 2KB
  float* psum = (float*)(smem + 65536 + 2048);  // 2KB

  const int tid = threadIdx.x;
  const int lane = tid & 63;
  const int w = tid >> 6;
  const int l15 = lane & 15;
  const int lh = lane >> 4;
  const long rowBase = (long)blockIdx.x * 64;

  // ---- Stage 1: h1 = leaky(x @ W1 + b1)  (x direct from HBM, W1 from L2)
  {
    f32x4 acc[4][4];
    #pragma unroll
    for (int mh = 0; mh < 4; ++mh)
      #pragma unroll
      for (int nt = 0; nt < 4; ++nt) acc[mh][nt] = f32x4{0.f, 0.f, 0.f, 0.f};
    const char* wl = (const char*)(ws + WS_W1) + (w * 64 + l15) * 64 + lh * 16;
    mlp_stage1(obs, act, rowBase, wl, acc, l15, lh);
    store_act<4>(acc, hbuf, bias1, w, l15, lh);
  }
  __syncthreads();

  // ---- Stage 2: h2 = leaky(h1 @ W2 + b2)
  {
    f32x4 acc[4][4];
    #pragma unroll
    for (int mh = 0; mh < 4; ++mh)
      #pragma unroll
      for (int nt = 0; nt < 4; ++nt) acc[mh][nt] = f32x4{0.f, 0.f, 0.f, 0.f};
    const char* wl = (const char*)(ws + WS_W2) + (w * 64 + l15) * 64 + lh * 16;
    mlp_stage_reg<16, 4>(wl, 32768, hbuf, 1024, acc, l15, lh);
    __syncthreads();   // all waves done reading h1
    store_act<4>(acc, hbuf, bias2, w, l15, lh);
  }
  __syncthreads();

  // ---- Stage 3: logits^T = (h2 @ W3 + b3)^T
  {
    f32x4 acc[4][2];
    #pragma unroll
    for (int mh = 0; mh < 4; ++mh)
      #pragma unroll
      for (int nt = 0; nt < 2; ++nt) acc[mh][nt] = f32x4{0.f, 0.f, 0.f, 0.f};
    const char* wl = (const char*)(ws + WS_W3) + (w * 32 + l15) * 64 + lh * 16;
    mlp_stage_reg<16, 2>(wl, 16384, hbuf, 1024, acc, l15, lh);
    __syncthreads();   // all waves done reading h2
    store_logits_T(acc, (float*)hbuf, bias3, w, l15, lh);
  }
  __syncthreads();

  // ---- Epilogue: lane-per-row softmax + projection; prT overlays lgT.
  {
    const float* lgT = (const float*)hbuf;
    float* prT = (float*)hbuf;
    const int a0 = w * 32;
    // pass 1: wave w's 32 atoms of row `lane` -> registers; partial max
    float e[32];
    #pragma unroll
    for (int i = 0; i < 32; ++i) e[i] = lgT[(a0 + i) * 64 + lane];
    float m0 = e[0], m1 = e[1], m2 = e[2], m3 = e[3];
    #pragma unroll
    for (int i = 4; i < 32; i += 4) {
      m0 = fmaxf(m0, e[i]);     m1 = fmaxf(m1, e[i + 1]);
      m2 = fmaxf(m2, e[i + 2]); m3 = fmaxf(m3, e[i + 3]);
    }
    pmax[w * 64 + lane] = fmaxf(fmaxf(m0, m1), fmaxf(m2, m3));
    float rw = rewards[rowBase + lane];
    float bd = __fmul_rn(bootstrap[rowBase + lane], discount[rowBase + lane]);
    __syncthreads();   // pmax visible; lgT fully consumed into registers

    // zero prT (overlay) + global max + exp + partial sum
    #pragma unroll
    for (int z = 0; z < 8; ++z)
      *(f32x4*)(hbuf + (z * 512 + tid) * 16) = f32x4{0.f, 0.f, 0.f, 0.f};
    float mx = pmax[lane];
    #pragma unroll
    for (int ww = 1; ww < 8; ++ww) mx = fmaxf(mx, pmax[ww * 64 + lane]);
    float s0 = 0.f, s1 = 0.f, s2 = 0.f, s3 = 0.f;
    #pragma unroll
    for (int i = 0; i < 32; i += 4) {
      e[i]     = __expf(e[i]     - mx); s0 += e[i];
      e[i + 1] = __expf(e[i + 1] - mx); s1 += e[i + 1];
      e[i + 2] = __expf(e[i + 2] - mx); s2 += e[i + 2];
      e[i + 3] = __expf(e[i + 3] - mx); s3 += e[i + 3];
    }
    psum[w * 64 + lane] = (s0 + s1) + (s2 + s3);
    __syncthreads();   // zeros + psum visible

    float tot = psum[lane];
    #pragma unroll
    for (int ww = 1; ww < 8; ++ww) tot += psum[ww * 64 + lane];
    float inv = 1.f / tot;

    // projection scatter (exact reference fp chain per element).
    // Addresses: distinct per lane within an instruction (row in low bits);
    // XOR keeps the out-read phase bank-spread.
    #pragma unroll
    for (int i = 0; i < 32; ++i) {
      int a = a0 + i;
      if (a < 251) {                     // wave-uniform guard
        float p = e[i] * inv;
        float zc = q_support[a];
        float tz = __fadd_rn(rw, __fmul_rn(bd, zc));
        tz = fminf(fmaxf(tz, -100.f), 100.f);
        float b = __fdiv_rn(__fadd_rn(tz, 100.f), 0.8f);
        float lf = floorf(b), uf = ceilf(b);
        int li = (int)lf, ui = (int)uf;
        bool eq = (li == ui);
        int li2 = li - ((eq && (ui > 0)) ? 1 : 0);
        int ui2 = ui + ((eq && (li < 250)) ? 1 : 0);
        atomicAdd(&prT[li2 * 64 + (lane ^ (li2 & 31))], p * ((float)ui2 - b));
        atomicAdd(&prT[ui2 * 64 + (lane ^ (ui2 & 31))], p * (b - (float)li2));
      }
    }
    __syncthreads();

    // coalesced output store
    for (unsigned i = tid; i < 64u * 251u; i += 512u) {
      unsigned row = i / 251u;
      unsigned c = i - row * 251u;
      out[rowBase * 251 + i] = prT[c * 64 + (row ^ (c & 31))];
    }
  }
}

extern "C" void kernel_launch(void* const* d_in, const int* in_sizes, int n_in,
                              void* d_out, int out_size, void* d_ws, size_t ws_size,
                              hipStream_t stream) {
  (void)n_in; (void)out_size; (void)ws_size;
  const float* obs       = (const float*)d_in[0];
  const float* actions   = (const float*)d_in[1];
  const float* rewards   = (const float*)d_in[2];
  const float* bootstrap = (const float*)d_in[3];
  const float* discount  = (const float*)d_in[4];
  const float* q_support = (const float*)d_in[5];
  const float* W1 = (const float*)d_in[6];
  const float* b1 = (const float*)d_in[7];
  const float* W2 = (const float*)d_in[8];
  const float* b2 = (const float*)d_in[9];
  const float* W3 = (const float*)d_in[10];
  const float* b3 = (const float*)d_in[11];
  float* out = (float*)d_out;
  f16* ws = (f16*)d_ws;
  const int B = in_sizes[2];

  hipLaunchKernelGGL(convert_weights_k, dim3(1792), dim3(256), 0, stream,
                     W1, W2, W3, ws);

  const int LDS_BYTES = 69632;  // 68 KB -> 2 blocks/CU
  hipFuncSetAttribute(reinterpret_cast<const void*>(fused_c51_k),
                      hipFuncAttributeMaxDynamicSharedMemorySize, LDS_BYTES);
  hipLaunchKernelGGL(fused_c51_k, dim3(B / 64), dim3(512), LDS_BYTES, stream,
                     obs, actions, rewards, bootstrap, discount, q_support,
                     b1, b2, b3, ws, out);
}